// Round 1
// baseline (190.160 us; speedup 1.0000x reference)
//
#include <hip/hip_runtime.h>
#include <math.h>

// Problem constants
// T=24, B=16, X=32, Y=32 -> N = 16384 sequences
// FS=64 (static spatial), FM=16, FC=16 -> I=96, H=32
//
// Strategy:
//  - pack_weights kernel: repack W_ih/W_hh into per-wave-chunk contiguous
//    layout in d_ws, fold biases.  (12,416 floats = 49,664 B of d_ws)
//  - gru_fused kernel: 256 blocks x 512 threads. lane(0..63)=sequence in
//    block, wave w(0..7) owns hidden units [4w,4w+4) i.e. 12 gate rows.
//    Spatial gi contribution computed ONCE before the t-loop (time-invariant).
//    Per step: 768 FMAs/lane (recurrent 32 cols + met 16 + ctx 16, x12 rows),
//    weights read at wave-uniform addresses -> scalar loads.
//    h exchanged across waves via double-buffered LDS (stride 33, conflict
//    free), one barrier per step.

#define OFF_PWS 0        // [8][64][12]
#define OFF_PWM 6144     // [8][16][12]
#define OFF_PWC 7680     // [8][16][12]
#define OFF_PWH 9216     // [8][32][12]
#define OFF_BAR 12288    // [8][4]  b_ih[k]+b_hh[k]        (r gate)
#define OFF_BAZ 12320    // [8][4]  b_ih[32+k]+b_hh[32+k]  (z gate)
#define OFF_BIN 12352    // [8][4]  b_ih[64+k]             (n gate, input side)
#define OFF_BHN 12384    // [8][4]  b_hh[64+k]             (n gate, hidden side)

__global__ void pack_weights(const float* __restrict__ W_ih,
                             const float* __restrict__ W_hh,
                             const float* __restrict__ b_ih,
                             const float* __restrict__ b_hh,
                             float* __restrict__ ws) {
  int idx = blockIdx.x * blockDim.x + threadIdx.x;
  for (int i = idx; i < 12288; i += gridDim.x * blockDim.x) {
    if (i < 6144) {                       // pwS: [w][j<64][r=g*4+u]
      int w = i / 768, rem = i % 768, j = rem / 12, r = rem % 12;
      int g = r >> 2, u = r & 3, row = g * 32 + 4 * w + u;
      ws[OFF_PWS + i] = W_ih[row * 96 + j];
    } else if (i < 7680) {                // pwM: [w][j<16][12]
      int t = i - 6144;
      int w = t / 192, rem = t % 192, j = rem / 12, r = rem % 12;
      int g = r >> 2, u = r & 3, row = g * 32 + 4 * w + u;
      ws[i] = W_ih[row * 96 + 64 + j];
    } else if (i < 9216) {                // pwC: [w][j<16][12]
      int t = i - 7680;
      int w = t / 192, rem = t % 192, j = rem / 12, r = rem % 12;
      int g = r >> 2, u = r & 3, row = g * 32 + 4 * w + u;
      ws[i] = W_ih[row * 96 + 80 + j];
    } else {                              // pwH: [w][j<32][12]
      int t = i - 9216;
      int w = t / 384, rem = t % 384, j = rem / 12, r = rem % 12;
      int g = r >> 2, u = r & 3, row = g * 32 + 4 * w + u;
      ws[i] = W_hh[row * 32 + j];
    }
  }
  if (idx < 32) {
    int w = idx >> 2, u = idx & 3, k = 4 * w + u;
    ws[OFF_BAR + idx] = b_ih[k] + b_hh[k];
    ws[OFF_BAZ + idx] = b_ih[32 + k] + b_hh[32 + k];
    ws[OFF_BIN + idx] = b_ih[64 + k];
    ws[OFF_BHN + idx] = b_hh[64 + k];
  }
}

__device__ __forceinline__ float sigf(float x) {
  return __builtin_amdgcn_rcpf(1.0f + __expf(-x));
}
__device__ __forceinline__ float tanh_fast(float x) {
  x = fminf(15.0f, fmaxf(-15.0f, x));
  float e = __expf(-2.0f * x);
  return (1.0f - e) * __builtin_amdgcn_rcpf(1.0f + e);
}

__global__ __launch_bounds__(512, 2)
void gru_fused(const float* __restrict__ spatial,
               const float* __restrict__ met,
               const float* __restrict__ ctx,
               const float* __restrict__ Wp,
               const float* __restrict__ pw,
               float* __restrict__ out) {
  __shared__ float hbuf[2][64 * 33];   // stride 33 -> conflict-free b32
  const int lane = threadIdx.x & 63;
  const int w = __builtin_amdgcn_readfirstlane(threadIdx.x >> 6);
  const int n = blockIdx.x * 64 + lane;

  const float* __restrict__ pwS = pw + OFF_PWS + w * (64 * 12);
  const float* __restrict__ pwM = pw + OFF_PWM + w * (16 * 12);
  const float* __restrict__ pwC = pw + OFF_PWC + w * (16 * 12);
  const float* __restrict__ pwH = pw + OFF_PWH + w * (32 * 12);

  // biases (folded); gr/gz/gn become the time-invariant gi_spatial + bias
  float gr[4], gz[4], gn[4], bhn[4];
#pragma unroll
  for (int u = 0; u < 4; ++u) {
    gr[u]  = pw[OFF_BAR + w * 4 + u];
    gz[u]  = pw[OFF_BAZ + w * 4 + u];
    gn[u]  = pw[OFF_BIN + w * 4 + u];
    bhn[u] = pw[OFF_BHN + w * 4 + u];
  }

  // one-time spatial contribution (time-invariant 64 of the 96 input cols)
  {
    float sp[64];
    const float4* sp4 = (const float4*)(spatial + (size_t)n * 64);
#pragma unroll
    for (int q = 0; q < 16; ++q) {
      float4 v = sp4[q];
      sp[4 * q] = v.x; sp[4 * q + 1] = v.y;
      sp[4 * q + 2] = v.z; sp[4 * q + 3] = v.w;
    }
#pragma unroll
    for (int j = 0; j < 64; ++j) {
      const float* wj = pwS + j * 12;
      float xv = sp[j];
#pragma unroll
      for (int u = 0; u < 4; ++u) {
        gr[u] = fmaf(wj[u],     xv, gr[u]);
        gz[u] = fmaf(wj[4 + u], xv, gz[u]);
        gn[u] = fmaf(wj[8 + u], xv, gn[u]);
      }
    }
  }

  float h[32];
#pragma unroll
  for (int j = 0; j < 32; ++j) h[j] = 0.0f;
  float hown[4] = {0.0f, 0.0f, 0.0f, 0.0f};  // this wave's own 4 h values

#pragma unroll 1
  for (int t = 0; t < 24; ++t) {
    // issue met/ctx loads early; recurrent FMAs below don't depend on them
    const float4* mp = (const float4*)(met + ((size_t)t * 16384 + n) * 16);
    const float4* cp = (const float4*)(ctx + ((size_t)t * 16384 + n) * 16);
    float4 mv[4], cv[4];
#pragma unroll
    for (int q = 0; q < 4; ++q) { mv[q] = mp[q]; cv[q] = cp[q]; }

    float ar[4], az[4], an[4], hn[4];
#pragma unroll
    for (int u = 0; u < 4; ++u) {
      ar[u] = gr[u]; az[u] = gz[u]; an[u] = gn[u]; hn[u] = bhn[u];
    }

    // recurrent part: 32 cols x 12 rows
#pragma unroll
    for (int j = 0; j < 32; ++j) {
      const float* wj = pwH + j * 12;
      float hv = h[j];
#pragma unroll
      for (int u = 0; u < 4; ++u) {
        ar[u] = fmaf(wj[u],     hv, ar[u]);
        az[u] = fmaf(wj[4 + u], hv, az[u]);
        hn[u] = fmaf(wj[8 + u], hv, hn[u]);
      }
    }

    float m[16], c[16];
#pragma unroll
    for (int q = 0; q < 4; ++q) {
      m[4 * q] = mv[q].x; m[4 * q + 1] = mv[q].y;
      m[4 * q + 2] = mv[q].z; m[4 * q + 3] = mv[q].w;
      c[4 * q] = cv[q].x; c[4 * q + 1] = cv[q].y;
      c[4 * q + 2] = cv[q].z; c[4 * q + 3] = cv[q].w;
    }
#pragma unroll
    for (int j = 0; j < 16; ++j) {
      const float* wj = pwM + j * 12;
      float xv = m[j];
#pragma unroll
      for (int u = 0; u < 4; ++u) {
        ar[u] = fmaf(wj[u],     xv, ar[u]);
        az[u] = fmaf(wj[4 + u], xv, az[u]);
        an[u] = fmaf(wj[8 + u], xv, an[u]);
      }
    }
#pragma unroll
    for (int j = 0; j < 16; ++j) {
      const float* wj = pwC + j * 12;
      float xv = c[j];
#pragma unroll
      for (int u = 0; u < 4; ++u) {
        ar[u] = fmaf(wj[u],     xv, ar[u]);
        az[u] = fmaf(wj[4 + u], xv, az[u]);
        an[u] = fmaf(wj[8 + u], xv, an[u]);
      }
    }

    // gates + state update for this wave's 4 hidden units
    float* hb = hbuf[t & 1];
#pragma unroll
    for (int u = 0; u < 4; ++u) {
      float r = sigf(ar[u]);
      float z = sigf(az[u]);
      float nn = tanh_fast(fmaf(r, hn[u], an[u]));
      float hv = fmaf(z, hown[u] - nn, nn);   // (1-z)*n + z*h
      hown[u] = hv;
      hb[lane * 33 + 4 * w + u] = hv;
    }
    __syncthreads();
#pragma unroll
    for (int j = 0; j < 32; ++j) h[j] = hb[lane * 33 + j];
  }

  // projection: out[n][8w .. 8w+8) = h . Wp[:, 8w..8w+8)
  float o[8];
#pragma unroll
  for (int f = 0; f < 8; ++f) o[f] = 0.0f;
#pragma unroll
  for (int j = 0; j < 32; ++j) {
    const float* wr = Wp + j * 64 + 8 * w;
    float hv = h[j];
#pragma unroll
    for (int f = 0; f < 8; ++f) o[f] = fmaf(hv, wr[f], o[f]);
  }
  float4* op = (float4*)(out + (size_t)n * 64 + 8 * w);
  op[0] = make_float4(o[0], o[1], o[2], o[3]);
  op[1] = make_float4(o[4], o[5], o[6], o[7]);
}

extern "C" void kernel_launch(void* const* d_in, const int* in_sizes, int n_in,
                              void* d_out, int out_size, void* d_ws, size_t ws_size,
                              hipStream_t stream) {
  const float* spatial = (const float*)d_in[0];
  const float* met     = (const float*)d_in[1];
  const float* ctx     = (const float*)d_in[2];
  const float* W_ih    = (const float*)d_in[3];
  const float* W_hh    = (const float*)d_in[4];
  const float* b_ih    = (const float*)d_in[5];
  const float* b_hh    = (const float*)d_in[6];
  const float* Wp      = (const float*)d_in[7];
  float* out = (float*)d_out;
  float* ws  = (float*)d_ws;

  hipLaunchKernelGGL(pack_weights, dim3(8), dim3(256), 0, stream,
                     W_ih, W_hh, b_ih, b_hh, ws);
  hipLaunchKernelGGL(gru_fused, dim3(256), dim3(512), 0, stream,
                     spatial, met, ctx, Wp, ws, out);
}

// Round 2
// 44.757 us; speedup vs baseline: 4.2488x; 4.2488x over previous
//
#include <hip/hip_runtime.h>
#include <math.h>

// T=24, B=16, X=32, Y=32 -> NSEQ=16384 sequences; FS=64, FM=16, FC=16 -> I=96; H=32.
//
// MFMA formulation (fp32 accuracy via bf16 hi/lo split, 3 MFMAs per product):
//   G_i[seq][96] = bias + spatial*Wsp^T (once) + x_mc(t)*Wmc^T (per step)
//   G_h[seq][96] = h(t)*Whh^T (+ b_hn on n rows)
//   r=sig(Gi_r+Gh_r); z=sig(Gi_z+Gh_z); n=tanh(Gi_n + r*Gh_n); h'=n+z*(h-n)
// Per block: 64 seqs, 512 thr (8 waves). wave w: seq-tile s=w>>1 (16 seqs),
// unit-half g=w&1 (units g*16..+16) -> row tiles {g,2+g,4+g} of the 6.
// Weights live in VGPR B-fragments for all 24 steps (no per-step refetch).
// h exchanged via stride-36 f32 LDS double buffer, 1 barrier/step.
// K-permutation within MFMA is irrelevant: A and B loaded with identical
// k-indexing, so any lane-internal k-order cancels in the dot product.

typedef __attribute__((ext_vector_type(8))) short short8;
typedef __attribute__((ext_vector_type(4))) float f32x4;

#define NSEQ 16384
#define TSTEPS 24

// ws layout (ushort elements)
#define W_HH_HI 0        // [96][32]
#define W_HH_LO 3072
#define W_MC_HI 6144     // [96][32]  (cols 64..95 of W_ih: 16 met + 16 ctx)
#define W_MC_LO 9216
#define W_SP_HI 12288    // [96][64]  (cols 0..63 of W_ih)
#define W_SP_LO 18432
// total 24576 ushorts = 49152 B

__device__ __forceinline__ unsigned short bf16_rn(float x) {
  unsigned u = __float_as_uint(x);
  u += 0x7FFFu + ((u >> 16) & 1u);
  return (unsigned short)(u >> 16);
}

__global__ void pack_w(const float* __restrict__ W_ih,
                       const float* __restrict__ W_hh,
                       unsigned short* __restrict__ ws) {
  int idx = blockIdx.x * blockDim.x + threadIdx.x;
  for (int i = idx; i < 12288; i += gridDim.x * blockDim.x) {
    float v; int slot_hi, slot_lo;
    if (i < 3072) {
      int row = i >> 5, k = i & 31;
      v = W_hh[row * 32 + k];
      slot_hi = W_HH_HI + i; slot_lo = W_HH_LO + i;
    } else if (i < 6144) {
      int j = i - 3072; int row = j >> 5, k = j & 31;
      v = W_ih[row * 96 + 64 + k];
      slot_hi = W_MC_HI + j; slot_lo = W_MC_LO + j;
    } else {
      int j = i - 6144; int row = j >> 6, k = j & 63;
      v = W_ih[row * 96 + k];
      slot_hi = W_SP_HI + j; slot_lo = W_SP_LO + j;
    }
    unsigned short h = bf16_rn(v);
    float hf = __uint_as_float(((unsigned)h) << 16);
    unsigned short l = bf16_rn(v - hf);
    ws[slot_hi] = h; ws[slot_lo] = l;
  }
}

__device__ __forceinline__ float sigf(float x) {
  return __builtin_amdgcn_rcpf(1.0f + __expf(-x));
}
__device__ __forceinline__ float tanh_fast(float x) {
  x = fminf(15.0f, fmaxf(-15.0f, x));
  float e = __expf(-2.0f * x);
  return (1.0f - e) * __builtin_amdgcn_rcpf(1.0f + e);
}

// hi = truncate-to-bf16(x); lo = bf16(x - hi). hi+lo represents x to ~2^-17 rel.
__device__ __forceinline__ void split8(float4 a, float4 b, short8& hi, short8& lo) {
  float f[8] = {a.x, a.y, a.z, a.w, b.x, b.y, b.z, b.w};
#pragma unroll
  for (int i = 0; i < 8; ++i) {
    unsigned u = __float_as_uint(f[i]);
    float hf = __uint_as_float(u & 0xFFFF0000u);
    hi[i] = (short)(u >> 16);
    lo[i] = (short)(__float_as_uint(f[i] - hf) >> 16);
  }
}

__device__ __forceinline__ f32x4 mfma16(short8 a, short8 b, f32x4 c) {
  return __builtin_amdgcn_mfma_f32_16x16x32_bf16(a, b, c, 0, 0, 0);
}

__global__ __launch_bounds__(512)
void gru_mfma(const float* __restrict__ spatial,
              const float* __restrict__ met,
              const float* __restrict__ ctx,
              const float* __restrict__ b_ih,
              const float* __restrict__ b_hh,
              const float* __restrict__ Wp,
              const unsigned short* __restrict__ ws,
              float* __restrict__ out) {
  __shared__ float hls[2][64 * 36];   // stride 36 dwords: balanced banks
  const int tid = threadIdx.x;
  const int lane = tid & 63;
  const int w = tid >> 6;       // 0..7
  const int s = w >> 1;         // seq-tile 0..3
  const int g = w & 1;          // unit half
  const int l15 = lane & 15;
  const int c = lane >> 4;      // 0..3
  const int unit = g * 16 + l15;
  const int seqbase = blockIdx.x * 64;
  const int seq_a = seqbase + s * 16 + l15;   // this lane's A-row (sequence)

  for (int i = tid; i < 64 * 36; i += 512) hls[0][i] = 0.0f;

  // persistent B-fragments: Whh and Wmc, hi/lo, for 3 row tiles
  short8 bhh_hi[3], bhh_lo[3], bmc_hi[3], bmc_lo[3];
#pragma unroll
  for (int j = 0; j < 3; ++j) {
    int rowb = j * 32 + g * 16 + l15;
    int off = rowb * 32 + c * 8;
    bhh_hi[j] = *(const short8*)(ws + W_HH_HI + off);
    bhh_lo[j] = *(const short8*)(ws + W_HH_LO + off);
    bmc_hi[j] = *(const short8*)(ws + W_MC_HI + off);
    bmc_lo[j] = *(const short8*)(ws + W_MC_LO + off);
  }

  // acc_i init: b_ih (all rows) + b_hh (r,z rows; n keeps b_hn separate)
  f32x4 acc_i[3];
#pragma unroll
  for (int j = 0; j < 3; ++j) {
    int row = j * 32 + unit;
    float bv = b_ih[row] + (j < 2 ? b_hh[row] : 0.0f);
    f32x4 v = {bv, bv, bv, bv};
    acc_i[j] = v;
  }
  float bhn = b_hh[64 + unit];
  f32x4 acc_h2 = {bhn, bhn, bhn, bhn};

  // fold time-invariant spatial contribution into acc_i (one-time MFMAs)
#pragma unroll
  for (int kt = 0; kt < 2; ++kt) {
    const float* sp = spatial + (size_t)seq_a * 64 + kt * 32 + c * 8;
    float4 a0 = *(const float4*)sp;
    float4 a1 = *(const float4*)(sp + 4);
    short8 ahi, alo;
    split8(a0, a1, ahi, alo);
#pragma unroll
    for (int j = 0; j < 3; ++j) {
      int rowb = j * 32 + g * 16 + l15;
      int off = rowb * 64 + kt * 32 + c * 8;
      short8 wh = *(const short8*)(ws + W_SP_HI + off);
      short8 wl = *(const short8*)(ws + W_SP_LO + off);
      acc_i[j] = mfma16(ahi, wh, acc_i[j]);
      acc_i[j] = mfma16(ahi, wl, acc_i[j]);
      acc_i[j] = mfma16(alo, wh, acc_i[j]);
    }
  }

  float hstate[4] = {0.f, 0.f, 0.f, 0.f};

  // stage t=0 met/ctx A-fragment (k 0..15 = met, 16..31 = ctx)
  const float* mcb = (c < 2) ? met : ctx;
  float4 m0, m1;
  {
    const float* p = mcb + ((size_t)0 * NSEQ + seq_a) * 16 + (c & 1) * 8;
    m0 = *(const float4*)p; m1 = *(const float4*)(p + 4);
  }
  __syncthreads();

#pragma unroll 1
  for (int t = 0; t < TSTEPS; ++t) {
    float4 n0, n1;
    if (t < TSTEPS - 1) {
      const float* p = mcb + ((size_t)(t + 1) * NSEQ + seq_a) * 16 + (c & 1) * 8;
      n0 = *(const float4*)p; n1 = *(const float4*)(p + 4);
    }
    // h A-fragment from LDS (f32, consumer-side hi/lo split)
    const float4* hp = (const float4*)&hls[t & 1][(s * 16 + l15) * 36 + c * 8];
    float4 h0 = hp[0], h1 = hp[1];
    short8 ah_hi, ah_lo, am_hi, am_lo;
    split8(h0, h1, ah_hi, ah_lo);
    split8(m0, m1, am_hi, am_lo);

    f32x4 ti[3], th[3];
#pragma unroll
    for (int j = 0; j < 3; ++j) {
      f32x4 a = mfma16(am_hi, bmc_hi[j], acc_i[j]);
      a = mfma16(am_hi, bmc_lo[j], a);
      ti[j] = mfma16(am_lo, bmc_hi[j], a);
      f32x4 z4 = {0.f, 0.f, 0.f, 0.f};
      f32x4 ch = (j == 2) ? acc_h2 : z4;
      f32x4 b = mfma16(ah_hi, bhh_hi[j], ch);
      b = mfma16(ah_hi, bhh_lo[j], b);
      th[j] = mfma16(ah_lo, bhh_hi[j], b);
    }

    float* hw = hls[(t + 1) & 1];
#pragma unroll
    for (int q = 0; q < 4; ++q) {
      float r = sigf(ti[0][q] + th[0][q]);
      float z = sigf(ti[1][q] + th[1][q]);
      float nn = tanh_fast(fmaf(r, th[2][q], ti[2][q]));
      float hv = nn + z * (hstate[q] - nn);
      hstate[q] = hv;
      hw[(s * 16 + c * 4 + q) * 36 + unit] = hv;
    }
    __syncthreads();
    if (t < TSTEPS - 1) { m0 = n0; m1 = n1; }
  }

  // projection: out[seq][64] = h . Wp  (fp32 VALU; weights wave-uniform)
  {
    const int seqp = tid & 63;
    const int wv = tid >> 6;
    float o[8];
#pragma unroll
    for (int f = 0; f < 8; ++f) o[f] = 0.0f;
#pragma unroll
    for (int j = 0; j < 32; ++j) {
      float hv = hls[0][seqp * 36 + j];   // final h lives in buffer 0 (24 even)
      const float* wr = Wp + j * 64 + 8 * wv;
#pragma unroll
      for (int f = 0; f < 8; ++f) o[f] = fmaf(hv, wr[f], o[f]);
    }
    float* op = out + (size_t)(seqbase + seqp) * 64 + 8 * wv;
    *(float4*)op = make_float4(o[0], o[1], o[2], o[3]);
    *(float4*)(op + 4) = make_float4(o[4], o[5], o[6], o[7]);
  }
}

extern "C" void kernel_launch(void* const* d_in, const int* in_sizes, int n_in,
                              void* d_out, int out_size, void* d_ws, size_t ws_size,
                              hipStream_t stream) {
  const float* spatial = (const float*)d_in[0];
  const float* met     = (const float*)d_in[1];
  const float* ctx     = (const float*)d_in[2];
  const float* W_ih    = (const float*)d_in[3];
  const float* W_hh    = (const float*)d_in[4];
  const float* b_ih    = (const float*)d_in[5];
  const float* b_hh    = (const float*)d_in[6];
  const float* Wp      = (const float*)d_in[7];
  float* out = (float*)d_out;
  unsigned short* ws = (unsigned short*)d_ws;

  hipLaunchKernelGGL(pack_w, dim3(16), dim3(256), 0, stream, W_ih, W_hh, ws);
  hipLaunchKernelGGL(gru_mfma, dim3(256), dim3(512), 0, stream,
                     spatial, met, ctx, b_ih, b_hh, Wp, ws, out);
}

// Round 3
// 40.526 us; speedup vs baseline: 4.6923x; 1.1044x over previous
//
#include <hip/hip_runtime.h>
#include <math.h>

// T=24, NSEQ=16384 (B*X*Y), FS=64, FM=16, FC=16 -> I=96; H=32.
//
// Swapped-operand MFMA GRU, fully in-register recurrence:
//   D[gate_row][seq] = W (A-operand) x data (B-operand), 16x16x32 bf16,
//   fp32 accuracy via hi/lo bf16 split (3 MFMAs per logical product).
// C/D layout (verified r2): lane(l15,c) holds seq=l15, rows 16j+4c+q.
// k-columns of W_hh (and rows of Wp) are permuted by
//   sigma(u) = 8*((u&15)>>2) + 4*(u>>4) + (u&3)
// so each lane's computed h'[u] values ARE its next-step B-fragment slots:
// elem e<4 -> u=4c+e (jj=0), e>=4 -> u=16+4c+(e-4) (jj=1).
// => no LDS, no barriers, no cross-lane ops in the recurrence.
// r,z gates: x-MFMAs and h-MFMAs chain into ONE accumulator (C-chaining).
// Wave = 16 seqs, block = 4 waves (64 seqs), grid = 256 -> waves independent.

typedef __attribute__((ext_vector_type(8))) short short8;
typedef __attribute__((ext_vector_type(4))) float f32x4;

#define NSEQ 16384
#define TSTEPS 24

// ws layout (ushort elements)
#define P_HH_HI 0        // [96][32] k-permuted by sigma
#define P_HH_LO 3072
#define P_MC_HI 6144     // [96][32] natural k (16 met + 16 ctx)
#define P_MC_LO 9216
#define P_SP_HI 12288    // [96][64] natural k
#define P_SP_LO 18432
#define P_WP_HI 24576    // [64][32] WpT, k-permuted by sigma
#define P_WP_LO 26624
// total 28672 ushorts = 57344 B

__device__ __forceinline__ unsigned short bf16_rn(float x) {
  unsigned u = __float_as_uint(x);
  u += 0x7FFFu + ((u >> 16) & 1u);
  return (unsigned short)(u >> 16);
}

__device__ __forceinline__ int sigma_inv(int ks) {
  int c = ks >> 3, e = ks & 7;
  return (e < 4) ? (4 * c + e) : (16 + 4 * c + (e - 4));
}

__global__ void pack_w(const float* __restrict__ W_ih,
                       const float* __restrict__ W_hh,
                       const float* __restrict__ Wp,
                       unsigned short* __restrict__ ws) {
  int idx = blockIdx.x * blockDim.x + threadIdx.x;
  for (int i = idx; i < 14336; i += gridDim.x * blockDim.x) {
    float v; int slot_hi, slot_lo;
    if (i < 3072) {                       // W_hh, sigma-permuted k
      int row = i >> 5, ks = i & 31;
      v = W_hh[row * 32 + sigma_inv(ks)];
      slot_hi = P_HH_HI + i; slot_lo = P_HH_LO + i;
    } else if (i < 6144) {                // W_ih cols 64..95 (met+ctx)
      int j = i - 3072; int row = j >> 5, k = j & 31;
      v = W_ih[row * 96 + 64 + k];
      slot_hi = P_MC_HI + j; slot_lo = P_MC_LO + j;
    } else if (i < 12288) {               // W_ih cols 0..63 (spatial)
      int j = i - 6144; int row = j >> 6, k = j & 63;
      v = W_ih[row * 96 + k];
      slot_hi = P_SP_HI + j; slot_lo = P_SP_LO + j;
    } else {                              // Wp^T, sigma-permuted k
      int j = i - 12288; int frow = j >> 5, ks = j & 31;
      v = Wp[sigma_inv(ks) * 64 + frow];
      slot_hi = P_WP_HI + j; slot_lo = P_WP_LO + j;
    }
    unsigned short h = bf16_rn(v);
    float hf = __uint_as_float(((unsigned)h) << 16);
    unsigned short l = bf16_rn(v - hf);
    ws[slot_hi] = h; ws[slot_lo] = l;
  }
}

__device__ __forceinline__ float sigf(float x) {
  return __builtin_amdgcn_rcpf(1.0f + __expf(-x));
}
__device__ __forceinline__ float tanh_fast(float x) {
  x = fminf(15.0f, fmaxf(-15.0f, x));
  float e = __expf(-2.0f * x);
  return (1.0f - e) * __builtin_amdgcn_rcpf(1.0f + e);
}

// hi = truncate-to-bf16(x); lo = bf16(x - hi)
__device__ __forceinline__ void split8(float4 a, float4 b, short8& hi, short8& lo) {
  float f[8] = {a.x, a.y, a.z, a.w, b.x, b.y, b.z, b.w};
#pragma unroll
  for (int i = 0; i < 8; ++i) {
    unsigned u = __float_as_uint(f[i]);
    float hf = __uint_as_float(u & 0xFFFF0000u);
    hi[i] = (short)(u >> 16);
    lo[i] = (short)(__float_as_uint(f[i] - hf) >> 16);
  }
}

__device__ __forceinline__ f32x4 mfma16(short8 a, short8 b, f32x4 c) {
  return __builtin_amdgcn_mfma_f32_16x16x32_bf16(a, b, c, 0, 0, 0);
}

__global__ __launch_bounds__(256)
void gru_reg(const float* __restrict__ spatial,
             const float* __restrict__ met,
             const float* __restrict__ ctx,
             const float* __restrict__ b_ih,
             const float* __restrict__ b_hh,
             const unsigned short* __restrict__ ws,
             float* __restrict__ out) {
  const int tid = threadIdx.x;
  const int lane = tid & 63;
  const int wv = tid >> 6;       // wave in block, 0..3
  const int l15 = lane & 15;
  const int c = lane >> 4;       // 0..3
  const int seq = blockIdx.x * 64 + wv * 16 + l15;

  // persistent A-fragments (weights): 6 row tiles x hi/lo x {hh, mc}
  short8 whh_hi[6], whh_lo[6], wmc_hi[6], wmc_lo[6];
#pragma unroll
  for (int j = 0; j < 6; ++j) {
    int off = (j * 16 + l15) * 32 + c * 8;
    whh_hi[j] = *(const short8*)(ws + P_HH_HI + off);
    whh_lo[j] = *(const short8*)(ws + P_HH_LO + off);
    wmc_hi[j] = *(const short8*)(ws + P_MC_HI + off);
    wmc_lo[j] = *(const short8*)(ws + P_MC_LO + off);
  }

  // acc_i init: bias (b_ih everywhere; + b_hh on r,z rows)
  f32x4 acc_i[6];
#pragma unroll
  for (int j = 0; j < 6; ++j) {
#pragma unroll
    for (int q = 0; q < 4; ++q) {
      int row = 16 * j + 4 * c + q;
      acc_i[j][q] = b_ih[row] + (j < 4 ? b_hh[row] : 0.0f);
    }
  }
  float bhn[8];
#pragma unroll
  for (int i = 0; i < 8; ++i) {
    int jj = i >> 2, q = i & 3;
    bhn[i] = b_hh[64 + 16 * jj + 4 * c + q];
  }

  // fold time-invariant spatial contribution (B = spatial fragment)
#pragma unroll
  for (int kt = 0; kt < 2; ++kt) {
    const float* sp = spatial + (size_t)seq * 64 + kt * 32 + c * 8;
    float4 a0 = *(const float4*)sp;
    float4 a1 = *(const float4*)(sp + 4);
    short8 shi, slo;
    split8(a0, a1, shi, slo);
#pragma unroll
    for (int j = 0; j < 6; ++j) {
      int off = (j * 16 + l15) * 64 + kt * 32 + c * 8;
      short8 wh = *(const short8*)(ws + P_SP_HI + off);
      short8 wl = *(const short8*)(ws + P_SP_LO + off);
      acc_i[j] = mfma16(wh, shi, acc_i[j]);
      acc_i[j] = mfma16(wl, shi, acc_i[j]);
      acc_i[j] = mfma16(wh, slo, acc_i[j]);
    }
  }

  float hst[8];
#pragma unroll
  for (int i = 0; i < 8; ++i) hst[i] = 0.0f;
  short8 hhi, hlo;
#pragma unroll
  for (int i = 0; i < 8; ++i) { hhi[i] = 0; hlo[i] = 0; }

  // per-lane met/ctx base: lanes c<2 read met feats 8c..8c+8, c>=2 ctx
  const float* mcb = ((c < 2) ? met : ctx) + (size_t)seq * 16 + (c & 1) * 8;
  float4 xa = *(const float4*)mcb;
  float4 xb = *(const float4*)(mcb + 4);

#pragma unroll 1
  for (int t = 0; t < TSTEPS; ++t) {
    float4 na, nb;
    if (t < TSTEPS - 1) {
      const float* p = mcb + (size_t)(t + 1) * NSEQ * 16;
      na = *(const float4*)p; nb = *(const float4*)(p + 4);
    }
    short8 xhi, xlo;
    split8(xa, xb, xhi, xlo);

    // r,z tiles (0..3): chain x and h products into one accumulator
    f32x4 dd[4];
#pragma unroll
    for (int j = 0; j < 4; ++j) {
      f32x4 a = mfma16(wmc_hi[j], xhi, acc_i[j]);
      a = mfma16(wmc_lo[j], xhi, a);
      a = mfma16(wmc_hi[j], xlo, a);
      a = mfma16(whh_hi[j], hhi, a);
      a = mfma16(whh_lo[j], hhi, a);
      dd[j] = mfma16(whh_hi[j], hlo, a);
    }
    // n tiles (4,5): keep input and hidden parts separate
    f32x4 ti[2], th[2];
#pragma unroll
    for (int jj = 0; jj < 2; ++jj) {
      int j = 4 + jj;
      f32x4 a = mfma16(wmc_hi[j], xhi, acc_i[j]);
      a = mfma16(wmc_lo[j], xhi, a);
      ti[jj] = mfma16(wmc_hi[j], xlo, a);
      f32x4 cb = {bhn[jj * 4 + 0], bhn[jj * 4 + 1], bhn[jj * 4 + 2], bhn[jj * 4 + 3]};
      f32x4 b = mfma16(whh_hi[j], hhi, cb);
      b = mfma16(whh_lo[j], hhi, b);
      th[jj] = mfma16(whh_hi[j], hlo, b);
    }

    // gates + state update; h' lands exactly in next B-fragment slots
#pragma unroll
    for (int jj = 0; jj < 2; ++jj) {
#pragma unroll
      for (int q = 0; q < 4; ++q) {
        int i = jj * 4 + q;
        float r = sigf(dd[jj][q]);
        float z = sigf(dd[2 + jj][q]);
        float nn = tanh_fast(fmaf(r, th[jj][q], ti[jj][q]));
        float hv = fmaf(z, hst[i] - nn, nn);
        hst[i] = hv;
        unsigned u = __float_as_uint(hv);
        float hf = __uint_as_float(u & 0xFFFF0000u);
        hhi[i] = (short)(u >> 16);
        hlo[i] = (short)(__float_as_uint(hv - hf) >> 16);
      }
    }
    xa = na; xb = nb;
  }

  // projection via MFMA: out^T[f][seq] = WpT (sigma-permuted) x h-fragment
  f32x4 o[4];
#pragma unroll
  for (int p = 0; p < 4; ++p) {
    int off = (p * 16 + l15) * 32 + c * 8;
    short8 ph = *(const short8*)(ws + P_WP_HI + off);
    short8 pl = *(const short8*)(ws + P_WP_LO + off);
    f32x4 z0 = {0.f, 0.f, 0.f, 0.f};
    f32x4 a = mfma16(ph, hhi, z0);
    a = mfma16(pl, hhi, a);
    o[p] = mfma16(ph, hlo, a);
  }
#pragma unroll
  for (int p = 0; p < 4; ++p) {
    float* op = out + (size_t)seq * 64 + p * 16 + 4 * c;
    *(float4*)op = make_float4(o[p][0], o[p][1], o[p][2], o[p][3]);
  }
}

extern "C" void kernel_launch(void* const* d_in, const int* in_sizes, int n_in,
                              void* d_out, int out_size, void* d_ws, size_t ws_size,
                              hipStream_t stream) {
  const float* spatial = (const float*)d_in[0];
  const float* met     = (const float*)d_in[1];
  const float* ctx     = (const float*)d_in[2];
  const float* W_ih    = (const float*)d_in[3];
  const float* W_hh    = (const float*)d_in[4];
  const float* b_ih    = (const float*)d_in[5];
  const float* b_hh    = (const float*)d_in[6];
  const float* Wp      = (const float*)d_in[7];
  float* out = (float*)d_out;
  unsigned short* ws = (unsigned short*)d_ws;

  hipLaunchKernelGGL(pack_w, dim3(16), dim3(256), 0, stream, W_ih, W_hh, Wp, ws);
  hipLaunchKernelGGL(gru_reg, dim3(256), dim3(256), 0, stream,
                     spatial, met, ctx, b_ih, b_hh, ws, out);
}

// Round 5
// 32.297 us; speedup vs baseline: 5.8879x; 1.2548x over previous
//
#include <hip/hip_runtime.h>
#include <hip/hip_fp16.h>
#include <math.h>

// T=24, NSEQ=16384, FS=64, FM=16, FC=16 -> I=96; H=32.
//
// 2-wave unit-split MFMA GRU (swapped operands, D[gate_row][seq]):
//  - block = 128 thr = wave pair; wave p computes units 16p..16p+16
//    (3 row tiles: r,z,n), 16 seqs per block -> 1024 blocks, 2048 waves
//    = 2 waves/SIMD (2x round-3 occupancy, half the work per wave).
//  - h' exchange: sigma k-permutation makes each lane's 4 computed h'
//    its own B-slots; partner wave's 4 come via LDS uint4 (same lane id),
//    double-buffered, 1 barrier/step.
//  - x-side: f16 single-term MFMA (weights pre-scaled), x packed to f16
//    once per block per step by a cooperative loader into LDS.
//  - h-side: bf16 hi/lo 3-term MFMA (round-3 proven numerics).
//  - gates: log2e folded into weights/biases -> sigmoid/tanh via exp2+rcp.

typedef __attribute__((ext_vector_type(8))) short short8;
typedef __attribute__((ext_vector_type(8))) _Float16 half8;
typedef __attribute__((ext_vector_type(4))) float f32x4;

#define NSEQ 16384
#define TSTEPS 24
#define LOG2E 1.44269504088896340736f

// ws layout (ushort units)
#define P_HH_HI 0        // [96][32] bf16-hi, scaled, sigma-k
#define P_HH_LO 3072
#define P_MC    6144     // [96][32] f16, scaled, natural k (met|ctx)
#define P_SP    9216     // [96][64] f16, scaled (spatial)
#define P_WP_HI 15360    // [64][32] bf16-hi, Wp^T sigma-k (unscaled)
#define P_WP_LO 17408
// total 19456 ushorts = 38912 B

__device__ __forceinline__ unsigned short bf16_rn(float x) {
  unsigned u = __float_as_uint(x);
  u += 0x7FFFu + ((u >> 16) & 1u);
  return (unsigned short)(u >> 16);
}
__device__ __forceinline__ int sigma_inv(int ks) {
  int cc = ks >> 3, e = ks & 7;
  return (e < 4) ? (4 * cc + e) : (16 + 4 * cc + (e - 4));
}

__global__ void pack_w(const float* __restrict__ W_ih,
                       const float* __restrict__ W_hh,
                       const float* __restrict__ Wp,
                       unsigned short* __restrict__ ws) {
  int idx = blockIdx.x * blockDim.x + threadIdx.x;
  for (int i = idx; i < 14336; i += gridDim.x * blockDim.x) {
    if (i < 3072) {                       // W_hh bf16 hi/lo, scaled, sigma-k
      int row = i >> 5, ks = i & 31;
      float sc = (row < 64) ? LOG2E : (2.0f * LOG2E);
      float v = W_hh[row * 32 + sigma_inv(ks)] * sc;
      unsigned short h = bf16_rn(v);
      float hf = __uint_as_float(((unsigned)h) << 16);
      ws[P_HH_HI + i] = h;
      ws[P_HH_LO + i] = bf16_rn(v - hf);
    } else if (i < 6144) {                // W_ih cols 64..95 -> f16 scaled
      int j = i - 3072;
      int row = j >> 5, k = j & 31;
      float sc = (row < 64) ? LOG2E : (2.0f * LOG2E);
      ws[P_MC + j] = __half_as_ushort(__float2half(W_ih[row * 96 + 64 + k] * sc));
    } else if (i < 12288) {               // W_ih cols 0..63 -> f16 scaled
      int j = i - 6144;
      int row = j >> 6, k = j & 63;
      float sc = (row < 64) ? LOG2E : (2.0f * LOG2E);
      ws[P_SP + j] = __half_as_ushort(__float2half(W_ih[row * 96 + k] * sc));
    } else {                              // Wp^T bf16 hi/lo, sigma-k
      int j = i - 12288;
      int frow = j >> 5, ks = j & 31;
      float v = Wp[sigma_inv(ks) * 64 + frow];
      unsigned short h = bf16_rn(v);
      float hf = __uint_as_float(((unsigned)h) << 16);
      ws[P_WP_HI + j] = h;
      ws[P_WP_LO + j] = bf16_rn(v - hf);
    }
  }
}

__device__ __forceinline__ float exp2_fast(float x) {
#if __has_builtin(__builtin_amdgcn_exp2f)
  return __builtin_amdgcn_exp2f(x);
#else
  return __expf(x * 0.6931471805599453f);
#endif
}

__device__ __forceinline__ unsigned int pk_f16(float a, float b) {
#if __has_builtin(__builtin_amdgcn_cvt_pkrtz)
  auto r = __builtin_amdgcn_cvt_pkrtz(a, b);   // __fp16 ext_vector(2)
  return __builtin_bit_cast(unsigned int, r);
#else
  return (unsigned)__half_as_ushort(__float2half(a)) |
         ((unsigned)__half_as_ushort(__float2half(b)) << 16);
#endif
}

__device__ __forceinline__ f32x4 mfma_bf(short8 a, short8 b, f32x4 c) {
  return __builtin_amdgcn_mfma_f32_16x16x32_bf16(a, b, c, 0, 0, 0);
}
__device__ __forceinline__ f32x4 mfma_h(half8 a, half8 b, f32x4 c) {
  return __builtin_amdgcn_mfma_f32_16x16x32_f16(a, b, c, 0, 0, 0);
}

union S8u { short8 v; unsigned int u[4]; };
union H8u { half8 v; unsigned int u[4]; };

__global__ __launch_bounds__(128, 2)
void gru2(const float* __restrict__ spatial,
          const float* __restrict__ met,
          const float* __restrict__ ctx,
          const float* __restrict__ b_ih,
          const float* __restrict__ b_hh,
          const unsigned short* __restrict__ ws,
          float* __restrict__ out) {
  __shared__ unsigned int hbuf[2][2][64][4];  // [buf][wave][lane][hi0,hi1,lo0,lo1]
  __shared__ unsigned int xb[2][16][16];      // [buf][seq][32 f16 feats]

  const int tid = threadIdx.x;
  const int lane = tid & 63;
  const int p = tid >> 6;            // wave 0/1 in the pair
  const int l15 = lane & 15;
  const int c = lane >> 4;           // 0..3
  const int seq0 = blockIdx.x * 16;
  const int seq = seq0 + l15;

  // zero initial-h buffer (read at t=0)
  for (int i = tid; i < 2 * 64 * 4; i += 128) ((unsigned int*)hbuf[1])[i] = 0u;

  // ---- persistent weights: 3 row tiles (r,z,n) for units 16p..16p+16 ----
  short8 whh_hi[3], whh_lo[3];
  half8 wmc[3];
#pragma unroll
  for (int g = 0; g < 3; ++g) {
    int row = g * 32 + p * 16 + l15;
    int off = row * 32 + c * 8;
    whh_hi[g] = *(const short8*)(ws + P_HH_HI + off);
    whh_lo[g] = *(const short8*)(ws + P_HH_LO + off);
    S8u t; t.v = *(const short8*)(ws + P_MC + off);
    H8u h; h.u[0] = t.u[0]; h.u[1] = t.u[1]; h.u[2] = t.u[2]; h.u[3] = t.u[3];
    wmc[g] = h.v;
  }

  // ---- bias init (scaled) ----
  f32x4 acc_i[3], bhn4;
#pragma unroll
  for (int g = 0; g < 3; ++g) {
#pragma unroll
    for (int q = 0; q < 4; ++q) {
      int row = g * 32 + p * 16 + 4 * c + q;
      float sc = (g < 2) ? LOG2E : (2.0f * LOG2E);
      acc_i[g][q] = (b_ih[row] + (g < 2 ? b_hh[row] : 0.0f)) * sc;
    }
  }
#pragma unroll
  for (int q = 0; q < 4; ++q)
    bhn4[q] = 2.0f * LOG2E * b_hh[64 + p * 16 + 4 * c + q];

  // ---- fold spatial (time-invariant) into acc_i, f16 single-term ----
#pragma unroll
  for (int kt = 0; kt < 2; ++kt) {
    const float* sp = spatial + (size_t)seq * 64 + kt * 32 + c * 8;
    float4 a0 = *(const float4*)sp;
    float4 a1 = *(const float4*)(sp + 4);
    H8u sf;
    sf.u[0] = pk_f16(a0.x, a0.y); sf.u[1] = pk_f16(a0.z, a0.w);
    sf.u[2] = pk_f16(a1.x, a1.y); sf.u[3] = pk_f16(a1.z, a1.w);
#pragma unroll
    for (int g = 0; g < 3; ++g) {
      int row = g * 32 + p * 16 + l15;
      S8u t; t.v = *(const short8*)(ws + P_SP + row * 64 + kt * 32 + c * 8);
      H8u wv; wv.u[0] = t.u[0]; wv.u[1] = t.u[1]; wv.u[2] = t.u[2]; wv.u[3] = t.u[3];
      acc_i[g] = mfma_h(wv.v, sf.v, acc_i[g]);
    }
  }

  // ---- x loader role: thread -> (seq lseq, feat-quad lf4) ----
  const int lseq = tid >> 3, lf4 = tid & 7;
  const float* lptr = ((lf4 < 4) ? met : ctx) +
                      (size_t)(seq0 + lseq) * 16 + (lf4 & 3) * 4;
  // stage x(0) into xb[0], keep x(1) in regs
  {
    float4 x0 = *(const float4*)lptr;
    xb[0][lseq][lf4 * 2]     = pk_f16(x0.x, x0.y);
    xb[0][lseq][lf4 * 2 + 1] = pk_f16(x0.z, x0.w);
  }
  float4 xn = *(const float4*)(lptr + (size_t)1 * NSEQ * 16);

  float hst[4] = {0.f, 0.f, 0.f, 0.f};
  unsigned int ohi0 = 0, ohi1 = 0, olo0 = 0, olo1 = 0;

  __syncthreads();

#pragma unroll 2
  for (int t = 0; t < TSTEPS; ++t) {
    // partner h' (previous step) + this step's x fragment
    uint4 ph = *(const uint4*)&hbuf[(t + 1) & 1][1 - p][lane][0];
    uint4 xv = *(const uint4*)&xb[t & 1][l15][c * 4];
    // prefetch x(t+2)
    int tf = (t + 2 < TSTEPS) ? (t + 2) : (TSTEPS - 1);
    float4 xn2 = *(const float4*)(lptr + (size_t)tf * NSEQ * 16);

    // build h fragments (own half + partner half)
    S8u fhi, flo;
    fhi.u[0] = p ? ph.x : ohi0;  fhi.u[1] = p ? ph.y : ohi1;
    fhi.u[2] = p ? ohi0 : ph.x;  fhi.u[3] = p ? ohi1 : ph.y;
    flo.u[0] = p ? ph.z : olo0;  flo.u[1] = p ? ph.w : olo1;
    flo.u[2] = p ? olo0 : ph.z;  flo.u[3] = p ? olo1 : ph.w;
    H8u xf; xf.u[0] = xv.x; xf.u[1] = xv.y; xf.u[2] = xv.z; xf.u[3] = xv.w;

    // x-part (f16 single) then h-part (bf16 3-term), 3 independent chains
    f32x4 dd0 = mfma_h(wmc[0], xf.v, acc_i[0]);
    f32x4 dd1 = mfma_h(wmc[1], xf.v, acc_i[1]);
    f32x4 tiv = mfma_h(wmc[2], xf.v, acc_i[2]);
    f32x4 thv = bhn4;
    dd0 = mfma_bf(whh_hi[0], fhi.v, dd0);
    dd1 = mfma_bf(whh_hi[1], fhi.v, dd1);
    thv = mfma_bf(whh_hi[2], fhi.v, thv);
    dd0 = mfma_bf(whh_lo[0], fhi.v, dd0);
    dd1 = mfma_bf(whh_lo[1], fhi.v, dd1);
    thv = mfma_bf(whh_lo[2], fhi.v, thv);
    dd0 = mfma_bf(whh_hi[0], flo.v, dd0);
    dd1 = mfma_bf(whh_hi[1], flo.v, dd1);
    thv = mfma_bf(whh_hi[2], flo.v, thv);

    // stage x(t+1) (regs from last step) into the other x buffer
    xb[(t + 1) & 1][lseq][lf4 * 2]     = pk_f16(xn.x, xn.y);
    xb[(t + 1) & 1][lseq][lf4 * 2 + 1] = pk_f16(xn.z, xn.w);

    // gates (weights pre-scaled by log2e / 2log2e)
    unsigned int hi[4], lo[4];
#pragma unroll
    for (int q = 0; q < 4; ++q) {
      float r = __builtin_amdgcn_rcpf(1.0f + exp2_fast(-dd0[q]));
      float z = __builtin_amdgcn_rcpf(1.0f + exp2_fast(-dd1[q]));
      float Y = fmaf(r, thv[q], tiv[q]);
      float e = fminf(exp2_fast(-Y), 1e30f);
      float nn = (1.0f - e) * __builtin_amdgcn_rcpf(1.0f + e);
      float hv = fmaf(z, hst[q] - nn, nn);
      hst[q] = hv;
      unsigned u = __float_as_uint(hv);
      hi[q] = u >> 16;                                   // bf16 hi (trunc)
      float hf = __uint_as_float(u & 0xFFFF0000u);
      lo[q] = __float_as_uint(hv - hf) >> 16;            // bf16 lo
    }
    ohi0 = hi[0] | (hi[1] << 16); ohi1 = hi[2] | (hi[3] << 16);
    olo0 = lo[0] | (lo[1] << 16); olo1 = lo[2] | (lo[3] << 16);
    *(uint4*)&hbuf[t & 1][p][lane][0] = make_uint4(ohi0, ohi1, olo0, olo1);

    __syncthreads();
    xn = xn2;
  }

  // ---- final h fragments (t=23 exchange already barriered) ----
  uint4 ph = *(const uint4*)&hbuf[1][1 - p][lane][0];   // 23&1 == 1
  S8u fhi, flo;
  fhi.u[0] = p ? ph.x : ohi0;  fhi.u[1] = p ? ph.y : ohi1;
  fhi.u[2] = p ? ohi0 : ph.x;  fhi.u[3] = p ? ohi1 : ph.y;
  flo.u[0] = p ? ph.z : olo0;  flo.u[1] = p ? ph.w : olo1;
  flo.u[2] = p ? olo0 : ph.z;  flo.u[3] = p ? olo1 : ph.w;

  // ---- projection: wave p does f-tiles {p, 2+p} (bf16 3-term) ----
#pragma unroll
  for (int pt = 0; pt < 2; ++pt) {
    int ftile = pt * 2 + p;
    int off = (ftile * 16 + l15) * 32 + c * 8;
    short8 wph = *(const short8*)(ws + P_WP_HI + off);
    short8 wpl = *(const short8*)(ws + P_WP_LO + off);
    f32x4 o = {0.f, 0.f, 0.f, 0.f};
    o = mfma_bf(wph, fhi.v, o);
    o = mfma_bf(wpl, fhi.v, o);
    o = mfma_bf(wph, flo.v, o);
    float* op = out + (size_t)seq * 64 + ftile * 16 + 4 * c;
    *(float4*)op = make_float4(o[0], o[1], o[2], o[3]);
  }
}

extern "C" void kernel_launch(void* const* d_in, const int* in_sizes, int n_in,
                              void* d_out, int out_size, void* d_ws, size_t ws_size,
                              hipStream_t stream) {
  const float* spatial = (const float*)d_in[0];
  const float* met     = (const float*)d_in[1];
  const float* ctx     = (const float*)d_in[2];
  const float* W_ih    = (const float*)d_in[3];
  const float* W_hh    = (const float*)d_in[4];
  const float* b_ih    = (const float*)d_in[5];
  const float* b_hh    = (const float*)d_in[6];
  const float* Wp      = (const float*)d_in[7];
  float* out = (float*)d_out;
  unsigned short* ws = (unsigned short*)d_ws;

  hipLaunchKernelGGL(pack_w, dim3(56), dim3(256), 0, stream, W_ih, W_hh, Wp, ws);
  hipLaunchKernelGGL(gru2, dim3(1024), dim3(128), 0, stream,
                     spatial, met, ctx, b_ih, b_hh, ws, out);
}

// Round 6
// 30.988 us; speedup vs baseline: 6.1365x; 1.0422x over previous
//
#include <hip/hip_runtime.h>
#include <hip/hip_fp16.h>
#include <math.h>

// T=24, NSEQ=16384, FS=64, FM=16, FC=16 -> I=96; H=32.
//
// 2-wave unit-split MFMA GRU (swapped operands, D[gate_row][seq]):
//  - block = 128 thr = wave pair; wave p computes units 16p..16p+16
//    (3 row tiles: r,z,n); 16 seqs/block -> 1024 blocks = 2048 waves
//    = 2 waves/SIMD.
//  - h' exchange: sigma k-permutation makes each lane's 4 computed h'
//    its own B-slots; partner wave's 4 via LDS uint4, double-buffered.
//  - Per-step sync: RAW s_barrier + lgkmcnt(0) ONLY (no vmcnt drain!) —
//    __syncthreads would drain the x prefetch every step (m97: compiler
//    emits vmcnt(0) before s_barrier). Global x loads stay in flight.
//  - x pipeline: 4-slot LDS ring, 2 loads in flight, load->use gap = 2 steps.
//  - x-side: f16 single-term MFMA; h-side: bf16 hi/lo 3-term.
//  - gates: log2e folded into weights; tanh = 2*rcp(1+exp2(-Y))-1.

typedef __attribute__((ext_vector_type(8))) short short8;
typedef __attribute__((ext_vector_type(8))) _Float16 half8;
typedef __attribute__((ext_vector_type(4))) float f32x4;

#define NSEQ 16384
#define TSTEPS 24
#define LOG2E 1.44269504088896340736f

// ws layout (ushort units)
#define P_HH_HI 0        // [96][32] bf16-hi, scaled, sigma-k
#define P_HH_LO 3072
#define P_MC    6144     // [96][32] f16, scaled, natural k (met|ctx)
#define P_SP    9216     // [96][64] f16, scaled (spatial)
#define P_WP_HI 15360    // [64][32] bf16-hi, Wp^T sigma-k (unscaled)
#define P_WP_LO 17408

__device__ __forceinline__ unsigned short bf16_rn(float x) {
  unsigned u = __float_as_uint(x);
  u += 0x7FFFu + ((u >> 16) & 1u);
  return (unsigned short)(u >> 16);
}
__device__ __forceinline__ int sigma_inv(int ks) {
  int cc = ks >> 3, e = ks & 7;
  return (e < 4) ? (4 * cc + e) : (16 + 4 * cc + (e - 4));
}

__global__ void pack_w(const float* __restrict__ W_ih,
                       const float* __restrict__ W_hh,
                       const float* __restrict__ Wp,
                       unsigned short* __restrict__ ws) {
  int idx = blockIdx.x * blockDim.x + threadIdx.x;
  for (int i = idx; i < 14336; i += gridDim.x * blockDim.x) {
    if (i < 3072) {                       // W_hh bf16 hi/lo, scaled, sigma-k
      int row = i >> 5, ks = i & 31;
      float sc = (row < 64) ? LOG2E : (2.0f * LOG2E);
      float v = W_hh[row * 32 + sigma_inv(ks)] * sc;
      unsigned short h = bf16_rn(v);
      float hf = __uint_as_float(((unsigned)h) << 16);
      ws[P_HH_HI + i] = h;
      ws[P_HH_LO + i] = bf16_rn(v - hf);
    } else if (i < 6144) {                // W_ih cols 64..95 -> f16 scaled
      int j = i - 3072;
      int row = j >> 5, k = j & 31;
      float sc = (row < 64) ? LOG2E : (2.0f * LOG2E);
      ws[P_MC + j] = __half_as_ushort(__float2half(W_ih[row * 96 + 64 + k] * sc));
    } else if (i < 12288) {               // W_ih cols 0..63 -> f16 scaled
      int j = i - 6144;
      int row = j >> 6, k = j & 63;
      float sc = (row < 64) ? LOG2E : (2.0f * LOG2E);
      ws[P_SP + j] = __half_as_ushort(__float2half(W_ih[row * 96 + k] * sc));
    } else {                              // Wp^T bf16 hi/lo, sigma-k
      int j = i - 12288;
      int frow = j >> 5, ks = j & 31;
      float v = Wp[sigma_inv(ks) * 64 + frow];
      unsigned short h = bf16_rn(v);
      float hf = __uint_as_float(((unsigned)h) << 16);
      ws[P_WP_HI + j] = h;
      ws[P_WP_LO + j] = bf16_rn(v - hf);
    }
  }
}

__device__ __forceinline__ float exp2_fast(float x) {
#if __has_builtin(__builtin_amdgcn_exp2f)
  return __builtin_amdgcn_exp2f(x);
#else
  return __expf(x * 0.6931471805599453f);
#endif
}

__device__ __forceinline__ unsigned int pk_f16(float a, float b) {
#if __has_builtin(__builtin_amdgcn_cvt_pkrtz)
  auto r = __builtin_amdgcn_cvt_pkrtz(a, b);   // __fp16 ext_vector(2)
  return __builtin_bit_cast(unsigned int, r);
#else
  return (unsigned)__half_as_ushort(__float2half(a)) |
         ((unsigned)__half_as_ushort(__float2half(b)) << 16);
#endif
}

__device__ __forceinline__ f32x4 mfma_bf(short8 a, short8 b, f32x4 c) {
  return __builtin_amdgcn_mfma_f32_16x16x32_bf16(a, b, c, 0, 0, 0);
}
__device__ __forceinline__ f32x4 mfma_h(half8 a, half8 b, f32x4 c) {
  return __builtin_amdgcn_mfma_f32_16x16x32_f16(a, b, c, 0, 0, 0);
}

// workgroup barrier that drains LDS ops only — keeps global prefetch in flight
__device__ __forceinline__ void barrier_lds() {
  asm volatile("s_waitcnt lgkmcnt(0)" ::: "memory");
  __builtin_amdgcn_s_barrier();
}

union S8u { short8 v; unsigned int u[4]; };
union H8u { half8 v; unsigned int u[4]; };

__global__ __launch_bounds__(128, 2)
void gru2(const float* __restrict__ spatial,
          const float* __restrict__ met,
          const float* __restrict__ ctx,
          const float* __restrict__ b_ih,
          const float* __restrict__ b_hh,
          const unsigned short* __restrict__ ws,
          float* __restrict__ out) {
  __shared__ unsigned int hbuf[2][2][64][4];  // [buf][wave][lane][hi0,hi1,lo0,lo1]
  __shared__ unsigned int xb[4][16][16];      // 4-slot ring [seq][32 f16 feats]

  const int tid = threadIdx.x;
  const int lane = tid & 63;
  const int p = tid >> 6;            // wave 0/1 in the pair
  const int l15 = lane & 15;
  const int c = lane >> 4;           // 0..3
  const int seq0 = blockIdx.x * 16;
  const int seq = seq0 + l15;

  // zero initial-h buffer (read at t=0)
  for (int i = tid; i < 2 * 64 * 4; i += 128) ((unsigned int*)hbuf[1])[i] = 0u;

  // ---- persistent weights: 3 row tiles (r,z,n) for units 16p..16p+16 ----
  short8 whh_hi[3], whh_lo[3];
  half8 wmc[3];
#pragma unroll
  for (int g = 0; g < 3; ++g) {
    int row = g * 32 + p * 16 + l15;
    int off = row * 32 + c * 8;
    whh_hi[g] = *(const short8*)(ws + P_HH_HI + off);
    whh_lo[g] = *(const short8*)(ws + P_HH_LO + off);
    S8u t; t.v = *(const short8*)(ws + P_MC + off);
    H8u h; h.u[0] = t.u[0]; h.u[1] = t.u[1]; h.u[2] = t.u[2]; h.u[3] = t.u[3];
    wmc[g] = h.v;
  }

  // ---- bias init (scaled) ----
  f32x4 acc_i[3], bhn4;
#pragma unroll
  for (int g = 0; g < 3; ++g) {
#pragma unroll
    for (int q = 0; q < 4; ++q) {
      int row = g * 32 + p * 16 + 4 * c + q;
      float sc = (g < 2) ? LOG2E : (2.0f * LOG2E);
      acc_i[g][q] = (b_ih[row] + (g < 2 ? b_hh[row] : 0.0f)) * sc;
    }
  }
#pragma unroll
  for (int q = 0; q < 4; ++q)
    bhn4[q] = 2.0f * LOG2E * b_hh[64 + p * 16 + 4 * c + q];

  // ---- fold spatial (time-invariant) into acc_i, f16 single-term ----
#pragma unroll
  for (int kt = 0; kt < 2; ++kt) {
    const float* sp = spatial + (size_t)seq * 64 + kt * 32 + c * 8;
    float4 a0 = *(const float4*)sp;
    float4 a1 = *(const float4*)(sp + 4);
    H8u sf;
    sf.u[0] = pk_f16(a0.x, a0.y); sf.u[1] = pk_f16(a0.z, a0.w);
    sf.u[2] = pk_f16(a1.x, a1.y); sf.u[3] = pk_f16(a1.z, a1.w);
#pragma unroll
    for (int g = 0; g < 3; ++g) {
      int row = g * 32 + p * 16 + l15;
      S8u t; t.v = *(const short8*)(ws + P_SP + row * 64 + kt * 32 + c * 8);
      H8u wv; wv.u[0] = t.u[0]; wv.u[1] = t.u[1]; wv.u[2] = t.u[2]; wv.u[3] = t.u[3];
      acc_i[g] = mfma_h(wv.v, sf.v, acc_i[g]);
    }
  }

  // ---- x loader role: thread -> (seq lseq, feat-quad lf4) ----
  const int lseq = tid >> 3, lf4 = tid & 7;
  const float* lptr = ((lf4 < 4) ? met : ctx) +
                      (size_t)(seq0 + lseq) * 16 + (lf4 & 3) * 4;
  // prologue: x(0), x(1) -> ring slots 0,1; x(2), x(3) in flight in regs
  {
    float4 x0 = *(const float4*)lptr;
    float4 x1 = *(const float4*)(lptr + (size_t)1 * NSEQ * 16);
    xb[0][lseq][lf4 * 2]     = pk_f16(x0.x, x0.y);
    xb[0][lseq][lf4 * 2 + 1] = pk_f16(x0.z, x0.w);
    xb[1][lseq][lf4 * 2]     = pk_f16(x1.x, x1.y);
    xb[1][lseq][lf4 * 2 + 1] = pk_f16(x1.z, x1.w);
  }
  float4 xfa = *(const float4*)(lptr + (size_t)2 * NSEQ * 16);  // x(t+2)
  float4 xfb = *(const float4*)(lptr + (size_t)3 * NSEQ * 16);  // x(t+3)

  float hst[4] = {0.f, 0.f, 0.f, 0.f};
  unsigned int ohi0 = 0, ohi1 = 0, olo0 = 0, olo1 = 0;

  barrier_lds();

#pragma unroll 4
  for (int t = 0; t < TSTEPS; ++t) {
    // partner h' (previous step) + this step's x fragment
    uint4 ph = *(const uint4*)&hbuf[(t + 1) & 1][1 - p][lane][0];
    uint4 xv = *(const uint4*)&xb[t & 3][l15][c * 4];

    // stage x(t+2) into the ring (load was issued 2 steps ago)
    if (t + 2 < TSTEPS) {
      xb[(t + 2) & 3][lseq][lf4 * 2]     = pk_f16(xfa.x, xfa.y);
      xb[(t + 2) & 3][lseq][lf4 * 2 + 1] = pk_f16(xfa.z, xfa.w);
    }
    xfa = xfb;
    // issue load of x(t+4) (stays in flight across raw barriers)
    int tf = (t + 4 < TSTEPS) ? (t + 4) : (TSTEPS - 1);
    xfb = *(const float4*)(lptr + (size_t)tf * NSEQ * 16);

    // build h fragments (own half + partner half)
    S8u fhi, flo;
    fhi.u[0] = p ? ph.x : ohi0;  fhi.u[1] = p ? ph.y : ohi1;
    fhi.u[2] = p ? ohi0 : ph.x;  fhi.u[3] = p ? ohi1 : ph.y;
    flo.u[0] = p ? ph.z : olo0;  flo.u[1] = p ? ph.w : olo1;
    flo.u[2] = p ? olo0 : ph.z;  flo.u[3] = p ? olo1 : ph.w;
    H8u xf; xf.u[0] = xv.x; xf.u[1] = xv.y; xf.u[2] = xv.z; xf.u[3] = xv.w;

    // x-part (f16 single) then h-part (bf16 3-term), 3 independent chains
    f32x4 dd0 = mfma_h(wmc[0], xf.v, acc_i[0]);
    f32x4 dd1 = mfma_h(wmc[1], xf.v, acc_i[1]);
    f32x4 tiv = mfma_h(wmc[2], xf.v, acc_i[2]);
    f32x4 thv = bhn4;
    dd0 = mfma_bf(whh_hi[0], fhi.v, dd0);
    dd1 = mfma_bf(whh_hi[1], fhi.v, dd1);
    thv = mfma_bf(whh_hi[2], fhi.v, thv);
    dd0 = mfma_bf(whh_lo[0], fhi.v, dd0);
    dd1 = mfma_bf(whh_lo[1], fhi.v, dd1);
    thv = mfma_bf(whh_lo[2], fhi.v, thv);
    dd0 = mfma_bf(whh_hi[0], flo.v, dd0);
    dd1 = mfma_bf(whh_hi[1], flo.v, dd1);
    thv = mfma_bf(whh_hi[2], flo.v, thv);

    // gates (weights pre-scaled by log2e / 2log2e); tanh = 2*sig(2x)-1
    unsigned int hi[4], lo[4];
#pragma unroll
    for (int q = 0; q < 4; ++q) {
      float r = __builtin_amdgcn_rcpf(1.0f + exp2_fast(-dd0[q]));
      float z = __builtin_amdgcn_rcpf(1.0f + exp2_fast(-dd1[q]));
      float Y = fmaf(r, thv[q], tiv[q]);
      float e = exp2_fast(-Y);
      float nn = fmaf(2.0f, __builtin_amdgcn_rcpf(1.0f + e), -1.0f);
      float hv = fmaf(z, hst[q] - nn, nn);
      hst[q] = hv;
      unsigned u = __float_as_uint(hv);
      hi[q] = u >> 16;                                   // bf16 hi (trunc)
      float hf = __uint_as_float(u & 0xFFFF0000u);
      lo[q] = __float_as_uint(hv - hf) >> 16;            // bf16 lo
    }
    ohi0 = hi[0] | (hi[1] << 16); ohi1 = hi[2] | (hi[3] << 16);
    olo0 = lo[0] | (lo[1] << 16); olo1 = lo[2] | (lo[3] << 16);
    *(uint4*)&hbuf[t & 1][p][lane][0] = make_uint4(ohi0, ohi1, olo0, olo1);

    barrier_lds();
  }

  // ---- final h fragments (t=23 exchange already barriered) ----
  uint4 ph = *(const uint4*)&hbuf[1][1 - p][lane][0];   // 23&1 == 1
  S8u fhi, flo;
  fhi.u[0] = p ? ph.x : ohi0;  fhi.u[1] = p ? ph.y : ohi1;
  fhi.u[2] = p ? ohi0 : ph.x;  fhi.u[3] = p ? ohi1 : ph.y;
  flo.u[0] = p ? ph.z : olo0;  flo.u[1] = p ? ph.w : olo1;
  flo.u[2] = p ? olo0 : ph.z;  flo.u[3] = p ? olo1 : ph.w;

  // ---- projection: wave p does f-tiles {p, 2+p} (bf16 3-term) ----
#pragma unroll
  for (int pt = 0; pt < 2; ++pt) {
    int ftile = pt * 2 + p;
    int off = (ftile * 16 + l15) * 32 + c * 8;
    short8 wph = *(const short8*)(ws + P_WP_HI + off);
    short8 wpl = *(const short8*)(ws + P_WP_LO + off);
    f32x4 o = {0.f, 0.f, 0.f, 0.f};
    o = mfma_bf(wph, fhi.v, o);
    o = mfma_bf(wpl, fhi.v, o);
    o = mfma_bf(wph, flo.v, o);
    float* op = out + (size_t)seq * 64 + ftile * 16 + 4 * c;
    *(float4*)op = make_float4(o[0], o[1], o[2], o[3]);
  }
}

extern "C" void kernel_launch(void* const* d_in, const int* in_sizes, int n_in,
                              void* d_out, int out_size, void* d_ws, size_t ws_size,
                              hipStream_t stream) {
  const float* spatial = (const float*)d_in[0];
  const float* met     = (const float*)d_in[1];
  const float* ctx     = (const float*)d_in[2];
  const float* W_ih    = (const float*)d_in[3];
  const float* W_hh    = (const float*)d_in[4];
  const float* b_ih    = (const float*)d_in[5];
  const float* b_hh    = (const float*)d_in[6];
  const float* Wp      = (const float*)d_in[7];
  float* out = (float*)d_out;
  unsigned short* ws = (unsigned short*)d_ws;

  hipLaunchKernelGGL(pack_w, dim3(56), dim3(256), 0, stream, W_ih, W_hh, Wp, ws);
  hipLaunchKernelGGL(gru2, dim3(1024), dim3(128), 0, stream,
                     spatial, met, ctx, b_ih, b_hh, ws, out);
}